// Round 4
// baseline (156.506 us; speedup 1.0000x reference)
//
#include <hip/hip_runtime.h>
#include <hip/hip_cooperative_groups.h>
#include <math.h>

namespace cg = cooperative_groups;

// ---------------------------------------------------------------------------
// B=32 queries [B,512] fp32 vs N=20000 keys [N,512] fp32.
// scores = Q K^T / sqrt(512); softmax over N; top-8; gather values rows.
// Output = [B*8 weights f32] ++ [B*8 * 10240 values f32].
//
// SINGLE cooperative kernel, 256 blocks x 256 threads (1 block/CU), phases
// separated by grid.sync() instead of kernel boundaries (R3 evidence: ~40us
// of the 59us total was inter-kernel gaps, kernel-interior work ~15us).
//  P0 qsplit:  blocks 0-31: q -> bf16 RNE to ws
//  P1 scores:  1024 waves sweep 1250 tiles (16 keys x 32 q, bf16 MFMA)
//  P2 part:    256 blocks == (row,chunk): online max/sum-exp + top-8
//  P3 final:   blocks 0-31 wave 0: merge 64 cands, exact fp32 rescore of
//              top-12, exact order/indices, weights
//  P4 gather:  2560 x 4KB segments, 10 per block
// ---------------------------------------------------------------------------

#define TOPK 8
#define DKD 512
#define NCHUNK 8
#define GRID 256

typedef __attribute__((ext_vector_type(8))) short short8;
typedef __attribute__((ext_vector_type(4))) float f32x4;

__device__ inline unsigned short f2bf(float x) {
    unsigned int u = __float_as_uint(x);
    u = (u + 0x7fffu + ((u >> 16) & 1u)) >> 16;   // RNE to bf16
    return (unsigned short)u;
}

// comparator everywhere: value desc, index asc (matches lax.top_k ties)
__device__ inline void wave_argmax(float& v, int& i) {
    #pragma unroll
    for (int off = 1; off < 64; off <<= 1) {
        float ov = __shfl_xor(v, off);
        int   oi = __shfl_xor(i, off);
        if (ov > v || (ov == v && oi < i)) { v = ov; i = oi; }
    }
}

__global__ __launch_bounds__(256, 1) void fused_kernel(
    const float* __restrict__ q, const float* __restrict__ keys,
    const float* __restrict__ values,
    unsigned short* __restrict__ qh, float* __restrict__ scores,
    float* __restrict__ pm, float* __restrict__ ps,
    float* __restrict__ cv, int* __restrict__ ci, int* __restrict__ tidx,
    float* __restrict__ out_w, float* __restrict__ out_v,
    int N, int LDV)
{
    cg::grid_group grid = cg::this_grid();
    const int bid  = blockIdx.x;
    const int tid  = threadIdx.x;
    const int lane = tid & 63;
    const int wid  = tid >> 6;
    const float scale = 0.04419417382415922f;   // 1/sqrt(512)

    __shared__ float lm[4], ls[4], lcv[4][TOPK];
    __shared__ int   lci[4][TOPK];

    // ---------------- P0: q -> bf16 (RNE) ----------------
    if (bid < 32 && tid < 128) {
        float4 v = *reinterpret_cast<const float4*>(&q[bid * DKD + tid * 4]);
        ushort4 h;
        h.x = f2bf(v.x); h.y = f2bf(v.y); h.z = f2bf(v.z); h.w = f2bf(v.w);
        *reinterpret_cast<ushort4*>(&qh[bid * DKD + tid * 4]) = h;
    }
    grid.sync();

    // ---------------- P1: approx scores via bf16 MFMA ----------------
    {
        const int col = lane & 15;           // key within tile / q-row in frags
        const int kg  = lane >> 4;           // k-chunk group 0..3
        const int ntiles = (N + 15) / 16;    // 1250

        for (int tile = bid * 4 + wid; tile < ntiles; tile += GRID * 4) {
            const int n0 = tile * 16;
            f32x4 acc0 = {0.f, 0.f, 0.f, 0.f};
            f32x4 acc1 = {0.f, 0.f, 0.f, 0.f};

            int nrow = n0 + col;
            const bool valid = (nrow < N);
            if (!valid) nrow = N - 1;
            const float*          krow = keys + (size_t)nrow * DKD + kg * 8;
            const unsigned short* q0   = qh + (size_t)col * DKD + kg * 8;
            const unsigned short* q1   = qh + (size_t)(col + 16) * DKD + kg * 8;

            #pragma unroll 4
            for (int ks = 0; ks < 16; ++ks) {
                const int d = ks * 32;
                float4 ka = *reinterpret_cast<const float4*>(krow + d);
                float4 kb = *reinterpret_cast<const float4*>(krow + d + 4);
                short8 fh;
                fh[0] = (short)f2bf(ka.x); fh[1] = (short)f2bf(ka.y);
                fh[2] = (short)f2bf(ka.z); fh[3] = (short)f2bf(ka.w);
                fh[4] = (short)f2bf(kb.x); fh[5] = (short)f2bf(kb.y);
                fh[6] = (short)f2bf(kb.z); fh[7] = (short)f2bf(kb.w);
                short8 a0 = *reinterpret_cast<const short8*>(q0 + d);
                short8 a1 = *reinterpret_cast<const short8*>(q1 + d);
                acc0 = __builtin_amdgcn_mfma_f32_16x16x32_bf16(a0, fh, acc0, 0, 0, 0);
                acc1 = __builtin_amdgcn_mfma_f32_16x16x32_bf16(a1, fh, acc1, 0, 0, 0);
            }

            // D layout (m89-verified): col = lane&15, row = (lane>>4)*4 + reg
            if (valid) {
                #pragma unroll
                for (int j = 0; j < 4; ++j) {
                    const int r = kg * 4 + j;
                    scores[(size_t)r * N + n0 + col]        = acc0[j] * scale;
                    scores[(size_t)(r + 16) * N + n0 + col] = acc1[j] * scale;
                }
            }
        }
    }
    grid.sync();

    // ---------------- P2: per (row, chunk) online max/sum-exp + top-8 ------
    {
        const int b = bid >> 3, c = bid & 7;
        const int chunk = N / NCHUNK;                  // 2500
        const float* base = scores + (size_t)b * N + c * chunk;
        const int i0 = c * chunk;
        const int n4 = chunk >> 2;                     // 625

        float m = -INFINITY, s = 0.0f;
        float v[TOPK];
        int   j[TOPK];
        #pragma unroll
        for (int k = 0; k < TOPK; ++k) { v[k] = -INFINITY; j[k] = 0x7fffffff; }

        for (int i = tid; i < n4; i += 256) {
            float4 x4 = reinterpret_cast<const float4*>(base)[i];
            float xs[4] = {x4.x, x4.y, x4.z, x4.w};
            #pragma unroll
            for (int e = 0; e < 4; ++e) {
                const float x = xs[e];
                const int  gi = i0 + i * 4 + e;
                const float nm = fmaxf(m, x);
                s = s * __expf(m - nm) + __expf(x - nm);
                m = nm;
                if (x > v[TOPK - 1]) {
                    bool g[TOPK];
                    #pragma unroll
                    for (int k = 0; k < TOPK; ++k) g[k] = (x > v[k]);
                    #pragma unroll
                    for (int k = TOPK - 1; k >= 1; --k) {
                        v[k] = g[k] ? (g[k - 1] ? v[k - 1] : x) : v[k];
                        j[k] = g[k] ? (g[k - 1] ? j[k - 1] : gi) : j[k];
                    }
                    v[0] = g[0] ? x : v[0];
                    j[0] = g[0] ? gi : j[0];
                }
            }
        }

        // wave-level (m,s) combine
        #pragma unroll
        for (int off = 1; off < 64; off <<= 1) {
            float om = __shfl_xor(m, off), os = __shfl_xor(s, off);
            float M2 = fmaxf(m, om);
            s = s * __expf(m - M2) + os * __expf(om - M2);
            m = M2;
        }

        // wave-level top-8 merge: 8 selection rounds over lanes' sorted lists
        float selv = 0.f; int seli = 0;
        #pragma unroll
        for (int r = 0; r < TOPK; ++r) {
            float mv = v[0]; int mi = j[0];
            wave_argmax(mv, mi);
            if (v[0] == mv && j[0] == mi) {            // I won: pop my head
                #pragma unroll
                for (int k = 0; k < TOPK - 1; ++k) { v[k] = v[k + 1]; j[k] = j[k + 1]; }
                v[TOPK - 1] = -INFINITY; j[TOPK - 1] = 0x7fffffff;
            }
            if (lane == r) { selv = mv; seli = mi; }
        }

        if (lane == 0) { lm[wid] = m; ls[wid] = s; }
        if (lane < TOPK) { lcv[wid][lane] = selv; lci[wid][lane] = seli; }
        __syncthreads();

        if (wid == 0) {
            if (lane == 0) {
                float M = lm[0], S = ls[0];
                #pragma unroll
                for (int cc = 1; cc < 4; ++cc) {
                    float M2 = fmaxf(M, lm[cc]);
                    S = S * __expf(M - M2) + ls[cc] * __expf(lm[cc] - M2);
                    M = M2;
                }
                pm[bid] = M; ps[bid] = S;
            }
            float vv = (lane < 32) ? lcv[lane >> 3][lane & 7] : -INFINITY;
            int   ii = (lane < 32) ? lci[lane >> 3][lane & 7] : 0x7fffffff;
            #pragma unroll
            for (int r = 0; r < TOPK; ++r) {
                float mv = vv; int mi = ii;
                wave_argmax(mv, mi);
                if (vv == mv && ii == mi) vv = -INFINITY;
                if (lane == r) { cv[bid * TOPK + r] = mv; ci[bid * TOPK + r] = mi; }
            }
        }
    }
    grid.sync();

    // ---------------- P3: final rescore + weights (blocks 0-31, wave 0) ----
    if (bid < 32 && wid == 0) {
        const int b = bid;
        float M = -INFINITY;
        #pragma unroll
        for (int c = 0; c < NCHUNK; ++c) M = fmaxf(M, pm[b * NCHUNK + c]);
        float S = 0.f;
        #pragma unroll
        for (int c = 0; c < NCHUNK; ++c)
            S += ps[b * NCHUNK + c] * __expf(pm[b * NCHUNK + c] - M);

        // 64 candidates, select approx top-12
        float vv = cv[b * 64 + lane];
        int   ii = ci[b * 64 + lane];
        int   si = 0x7fffffff;
        #pragma unroll
        for (int r = 0; r < 12; ++r) {
            float mv = vv; int mi = ii;
            wave_argmax(mv, mi);
            if (vv == mv && ii == mi) vv = -INFINITY;
            if (lane == r) si = mi;
        }

        // exact fp32 rescore of the 12 candidates
        float4 qa = *reinterpret_cast<const float4*>(q + (size_t)b * DKD + lane * 8);
        float4 qb = *reinterpret_cast<const float4*>(q + (size_t)b * DKD + lane * 8 + 4);
        float exv = -INFINITY;
        #pragma unroll
        for (int r = 0; r < 12; ++r) {
            const int cand = __shfl(si, r);
            const float* kr = keys + (size_t)cand * DKD + lane * 8;
            float4 k1 = *reinterpret_cast<const float4*>(kr);
            float4 k2 = *reinterpret_cast<const float4*>(kr + 4);
            float p = qa.x * k1.x + qa.y * k1.y + qa.z * k1.z + qa.w * k1.w
                    + qb.x * k2.x + qb.y * k2.y + qb.z * k2.z + qb.w * k2.w;
            #pragma unroll
            for (int off = 1; off < 64; off <<= 1) p += __shfl_xor(p, off);
            if (lane == r) exv = p * scale;
        }

        // exact top-8 of 12, emit weights (max M cancels num/denom)
        float fv = (lane < 12) ? exv : -INFINITY;
        int   fi = (lane < 12) ? si : 0x7fffffff;
        #pragma unroll
        for (int r = 0; r < TOPK; ++r) {
            float mv = fv; int mi = fi;
            wave_argmax(mv, mi);
            if (fv == mv && fi == mi) fv = -INFINITY;
            if (lane == r) {
                out_w[b * TOPK + r] = __expf(mv - M) / S;
                tidx[b * TOPK + r]  = mi;
            }
        }
    }
    grid.sync();

    // ---------------- P4: gather (2560 x 4KB segments, 10 per block) -------
    {
        const int segs_per_row = LDV / 1024;           // 10
        #pragma unroll
        for (int i = 0; i < 10; ++i) {
            const int s  = bid + i * GRID;             // 0..2559
            const int bk = s / 10;
            const int pt = s - bk * 10;
            const int id = tidx[bk];
            const float4* src = reinterpret_cast<const float4*>(
                values + (size_t)id * LDV + (size_t)pt * 1024);
            float4* dst = reinterpret_cast<float4*>(
                out_v + (size_t)bk * LDV + (size_t)pt * 1024);
            dst[tid] = src[tid];
        }
        (void)segs_per_row;
    }
}

extern "C" void kernel_launch(void* const* d_in, const int* in_sizes, int n_in,
                              void* d_out, int out_size, void* d_ws, size_t ws_size,
                              hipStream_t stream) {
    const float* q      = (const float*)d_in[0];
    const float* keys   = (const float*)d_in[1];
    const float* values = (const float*)d_in[2];

    const int B   = in_sizes[0] / DKD;                 // 32
    const int N   = in_sizes[1] / DKD;                 // 20000
    const int LDV = (int)((long long)in_sizes[2] / N); // 10240

    float* out   = (float*)d_out;
    float* out_w = out;
    float* out_v = out + (size_t)B * TOPK;

    char* wsb = (char*)d_ws;
    size_t off = 0;
    float* scores = (float*)(wsb + off); off += (size_t)B * N * sizeof(float);
    unsigned short* qh = (unsigned short*)(wsb + off); off += (size_t)B * DKD * 2;
    float* pm = (float*)(wsb + off); off += (size_t)B * NCHUNK * sizeof(float);
    float* ps = (float*)(wsb + off); off += (size_t)B * NCHUNK * sizeof(float);
    float* cv = (float*)(wsb + off); off += (size_t)B * NCHUNK * TOPK * sizeof(float);
    int*   ci = (int*)(wsb + off);   off += (size_t)B * NCHUNK * TOPK * sizeof(int);
    int*   tidx = (int*)(wsb + off); off += (size_t)B * TOPK * sizeof(int);

    void* args[] = {
        (void*)&q, (void*)&keys, (void*)&values,
        (void*)&qh, (void*)&scores, (void*)&pm, (void*)&ps,
        (void*)&cv, (void*)&ci, (void*)&tidx,
        (void*)&out_w, (void*)&out_v,
        (void*)&N, (void*)&LDV
    };
    hipLaunchCooperativeKernel((const void*)fused_kernel,
                               dim3(GRID), dim3(256), args, 0, stream);
}

// Round 5
// 77.863 us; speedup vs baseline: 2.0100x; 2.0100x over previous
//
#include <hip/hip_runtime.h>
#include <math.h>

// ---------------------------------------------------------------------------
// B=32 queries [B,512] fp32 vs N=20000 keys [N,512] fp32.
// scores = Q K^T / sqrt(512); softmax over N; top-8; gather values rows.
// Output = [B*8 weights f32] ++ [B*8 * 10240 values f32].
//
// 3-kernel pipeline (R5: discriminate inter-kernel-gap vs fixed-overhead):
//  K1 scores:  fused q->bf16 convert + bf16 MFMA, 16 keys/wave   (313 blk)
//  K2 row:     per-row stream softmax stats + reg top-8 + wave
//              merges -> 32 cands -> top-12 -> EXACT fp32
//              rescore -> weights + indices                      (32 blk)
//  K3 gather:  values[idx] rows, 4 blocks/row                    (1024 blk)
// ---------------------------------------------------------------------------

#define TOPK 8
#define DKD 512

typedef __attribute__((ext_vector_type(8))) short short8;
typedef __attribute__((ext_vector_type(4))) float f32x4;

__device__ inline unsigned short f2bf(float x) {
    unsigned int u = __float_as_uint(x);
    u = (u + 0x7fffu + ((u >> 16) & 1u)) >> 16;   // RNE to bf16
    return (unsigned short)u;
}

__device__ inline short8 cvt8(float4 a, float4 b) {
    short8 r;
    r[0] = (short)f2bf(a.x); r[1] = (short)f2bf(a.y);
    r[2] = (short)f2bf(a.z); r[3] = (short)f2bf(a.w);
    r[4] = (short)f2bf(b.x); r[5] = (short)f2bf(b.y);
    r[6] = (short)f2bf(b.z); r[7] = (short)f2bf(b.w);
    return r;
}

// comparator everywhere: value desc, index asc (matches lax.top_k ties)
__device__ inline void wave_argmax(float& v, int& i) {
    #pragma unroll
    for (int off = 1; off < 64; off <<= 1) {
        float ov = __shfl_xor(v, off);
        int   oi = __shfl_xor(i, off);
        if (ov > v || (ov == v && oi < i)) { v = ov; i = oi; }
    }
}

// ---- K1: approx scores via bf16 MFMA, q converted in-kernel ----------------
// 4 waves/block; each wave: 16 keys x 32 queries x K=512.
__global__ __launch_bounds__(256) void scores_kernel(
    const float* __restrict__ keys, const float* __restrict__ q,
    float* __restrict__ scores, int N)
{
    const int lane = threadIdx.x & 63;
    const int wid  = threadIdx.x >> 6;
    const int col  = lane & 15;            // key within tile / q-row in frags
    const int kg   = lane >> 4;            // k-chunk group 0..3
    const float scale = 0.04419417382415922f; // 1/sqrt(512)
    const int ntiles = (N + 15) / 16;      // 1250

    for (int tile = blockIdx.x * 4 + wid; tile < ntiles; tile += gridDim.x * 4) {
        const int n0 = tile * 16;
        f32x4 acc0 = {0.f, 0.f, 0.f, 0.f};
        f32x4 acc1 = {0.f, 0.f, 0.f, 0.f};

        int nrow = n0 + col;
        const bool valid = (nrow < N);
        if (!valid) nrow = N - 1;          // clamp loads, skip stores
        const float* krow = keys + (size_t)nrow * DKD + kg * 8;
        const float* q0   = q + (size_t)col * DKD + kg * 8;
        const float* q1   = q + (size_t)(col + 16) * DKD + kg * 8;

        #pragma unroll 2
        for (int ks = 0; ks < 16; ++ks) {
            const int d = ks * 32;
            float4 ka = *reinterpret_cast<const float4*>(krow + d);
            float4 kb = *reinterpret_cast<const float4*>(krow + d + 4);
            float4 qa = *reinterpret_cast<const float4*>(q0 + d);
            float4 qb = *reinterpret_cast<const float4*>(q0 + d + 4);
            float4 qc = *reinterpret_cast<const float4*>(q1 + d);
            float4 qd = *reinterpret_cast<const float4*>(q1 + d + 4);
            short8 fh = cvt8(ka, kb);
            short8 a0 = cvt8(qa, qb);
            short8 a1 = cvt8(qc, qd);
            acc0 = __builtin_amdgcn_mfma_f32_16x16x32_bf16(a0, fh, acc0, 0, 0, 0);
            acc1 = __builtin_amdgcn_mfma_f32_16x16x32_bf16(a1, fh, acc1, 0, 0, 0);
        }

        // D layout (m89-verified): col = lane&15, row = (lane>>4)*4 + reg
        if (valid) {
            #pragma unroll
            for (int j = 0; j < 4; ++j) {
                const int r = kg * 4 + j;
                scores[(size_t)r * N + n0 + col]        = acc0[j] * scale;
                scores[(size_t)(r + 16) * N + n0 + col] = acc1[j] * scale;
            }
        }
    }
}

// ---- K2: per-row softmax stats + top-8 + exact rescore + weights ----------
// One block (256 thr) per query row.
__global__ __launch_bounds__(256) void row_kernel(
    const float* __restrict__ scores, const float* __restrict__ q,
    const float* __restrict__ keys, float* __restrict__ out_w,
    int* __restrict__ tidx, int N)
{
    const int b    = blockIdx.x;
    const int tid  = threadIdx.x;
    const int lane = tid & 63;
    const int wid  = tid >> 6;
    const float scale = 0.04419417382415922f;
    const float* row = scores + (size_t)b * N;
    const int n4 = N >> 2;

    __shared__ float lm[4], ls[4], lcv[4][TOPK];
    __shared__ int   lci[4][TOPK];

    // ---- stream: online (m,s) + per-thread top-8 ----
    float m = -INFINITY, s = 0.0f;
    float v[TOPK];
    int   j[TOPK];
    #pragma unroll
    for (int k = 0; k < TOPK; ++k) { v[k] = -INFINITY; j[k] = 0x7fffffff; }

    for (int i = tid; i < n4; i += 256) {
        float4 x4 = reinterpret_cast<const float4*>(row)[i];
        float xs[4] = {x4.x, x4.y, x4.z, x4.w};
        #pragma unroll
        for (int e = 0; e < 4; ++e) {
            const float x = xs[e];
            const int  gi = i * 4 + e;
            const float nm = fmaxf(m, x);
            s = s * __expf(m - nm) + __expf(x - nm);
            m = nm;
            if (x > v[TOPK - 1]) {
                bool g[TOPK];
                #pragma unroll
                for (int k = 0; k < TOPK; ++k) g[k] = (x > v[k]);
                #pragma unroll
                for (int k = TOPK - 1; k >= 1; --k) {
                    v[k] = g[k] ? (g[k - 1] ? v[k - 1] : x) : v[k];
                    j[k] = g[k] ? (g[k - 1] ? j[k - 1] : gi) : j[k];
                }
                v[0] = g[0] ? x : v[0];
                j[0] = g[0] ? gi : j[0];
            }
        }
    }
    for (int i = 4 * n4 + tid; i < N; i += 256) {   // tail (N%4)
        const float x = row[i];
        const float nm = fmaxf(m, x);
        s = s * __expf(m - nm) + __expf(x - nm);
        m = nm;
        if (x > v[TOPK - 1]) {
            int k = TOPK - 1;
            while (k > 0 && v[k - 1] < x) { v[k] = v[k - 1]; j[k] = j[k - 1]; --k; }
            v[k] = x; j[k] = i;
        }
    }

    // ---- wave-level (m,s) combine ----
    #pragma unroll
    for (int off = 1; off < 64; off <<= 1) {
        float om = __shfl_xor(m, off), os = __shfl_xor(s, off);
        float M2 = fmaxf(m, om);
        s = s * __expf(m - M2) + os * __expf(om - M2);
        m = M2;
    }

    // ---- wave-level top-8 merge: 8 selection rounds ----
    float selv = 0.f; int seli = 0;
    #pragma unroll
    for (int r = 0; r < TOPK; ++r) {
        float mv = v[0]; int mi = j[0];
        wave_argmax(mv, mi);
        if (v[0] == mv && j[0] == mi) {            // I won: pop my head
            #pragma unroll
            for (int k = 0; k < TOPK - 1; ++k) { v[k] = v[k + 1]; j[k] = j[k + 1]; }
            v[TOPK - 1] = -INFINITY; j[TOPK - 1] = 0x7fffffff;
        }
        if (lane == r) { selv = mv; seli = mi; }
    }

    if (lane == 0) { lm[wid] = m; ls[wid] = s; }
    if (lane < TOPK) { lcv[wid][lane] = selv; lci[wid][lane] = seli; }
    __syncthreads();

    if (wid != 0) return;

    // ---- cross-wave combine (all lanes of wave 0 redundantly) ----
    float M = lm[0], S = ls[0];
    #pragma unroll
    for (int cc = 1; cc < 4; ++cc) {
        float M2 = fmaxf(M, lm[cc]);
        S = S * __expf(M - M2) + ls[cc] * __expf(lm[cc] - M2);
        M = M2;
    }

    // ---- 32 candidates -> approx top-12 ----
    float vv = (lane < 32) ? lcv[lane >> 3][lane & 7] : -INFINITY;
    int   ii = (lane < 32) ? lci[lane >> 3][lane & 7] : 0x7fffffff;
    int   si = 0x7fffffff;
    #pragma unroll
    for (int r = 0; r < 12; ++r) {
        float mv = vv; int mi = ii;
        wave_argmax(mv, mi);
        if (vv == mv && ii == mi) vv = -INFINITY;
        if (lane == r) si = mi;
    }

    // ---- exact fp32 rescore of the 12 candidates ----
    float4 qa = *reinterpret_cast<const float4*>(q + (size_t)b * DKD + lane * 8);
    float4 qb = *reinterpret_cast<const float4*>(q + (size_t)b * DKD + lane * 8 + 4);
    float exv = -INFINITY;
    #pragma unroll
    for (int r = 0; r < 12; ++r) {
        const int cand = __shfl(si, r);
        const float* kr = keys + (size_t)cand * DKD + lane * 8;
        float4 k1 = *reinterpret_cast<const float4*>(kr);
        float4 k2 = *reinterpret_cast<const float4*>(kr + 4);
        float p = qa.x * k1.x + qa.y * k1.y + qa.z * k1.z + qa.w * k1.w
                + qb.x * k2.x + qb.y * k2.y + qb.z * k2.z + qb.w * k2.w;
        #pragma unroll
        for (int off = 1; off < 64; off <<= 1) p += __shfl_xor(p, off);
        if (lane == r) exv = p * scale;
    }

    // ---- exact top-8 of 12, emit weights (max M cancels num/denom) ----
    float fv = (lane < 12) ? exv : -INFINITY;
    int   fi = (lane < 12) ? si : 0x7fffffff;
    #pragma unroll
    for (int r = 0; r < TOPK; ++r) {
        float mv = fv; int mi = fi;
        wave_argmax(mv, mi);
        if (fv == mv && fi == mi) fv = -INFINITY;
        if (lane == r) {
            out_w[b * TOPK + r] = __expf(mv - M) / S;
            tidx[b * TOPK + r]  = mi;
        }
    }
}

// ---- K3: gather values rows (4 blocks per output row) ---------------------
__global__ __launch_bounds__(256) void gather_kernel(
    const float* __restrict__ values, const int* __restrict__ idx,
    float* __restrict__ out, int LDV)
{
    const int bk  = blockIdx.x >> 2;
    const int qtr = blockIdx.x & 3;
    const int id = idx[bk];
    const float4* src = reinterpret_cast<const float4*>(values + (size_t)id * LDV);
    float4*       dst = reinterpret_cast<float4*>(out + (size_t)bk * LDV);
    const int n4 = LDV >> 2;                 // 2560
    const int qn = n4 >> 2;                  // 640
    for (int i = qtr * qn + threadIdx.x; i < (qtr + 1) * qn; i += 256)
        dst[i] = src[i];
}

extern "C" void kernel_launch(void* const* d_in, const int* in_sizes, int n_in,
                              void* d_out, int out_size, void* d_ws, size_t ws_size,
                              hipStream_t stream) {
    const float* q      = (const float*)d_in[0];
    const float* keys   = (const float*)d_in[1];
    const float* values = (const float*)d_in[2];

    const int B   = in_sizes[0] / DKD;                 // 32
    const int N   = in_sizes[1] / DKD;                 // 20000
    const int LDV = (int)((long long)in_sizes[2] / N); // 10240

    float* out   = (float*)d_out;
    float* out_w = out;
    float* out_v = out + (size_t)B * TOPK;

    char* wsb = (char*)d_ws;
    size_t off = 0;
    float* scores = (float*)(wsb + off); off += (size_t)B * N * sizeof(float);
    int*   tidx   = (int*)(wsb + off);   off += (size_t)B * TOPK * sizeof(int);

    const int ntiles = (N + 15) / 16;                  // 1250
    scores_kernel<<<(ntiles + 3) / 4, 256, 0, stream>>>(keys, q, scores, N);
    row_kernel<<<B, 256, 0, stream>>>(scores, q, keys, out_w, tidx, N);
    gather_kernel<<<B * TOPK * 4, 256, 0, stream>>>(values, tidx, out_v, LDV);
}